// Round 1
// baseline (388.393 us; speedup 1.0000x reference)
//
#include <hip/hip_runtime.h>

// Problem constants (match reference)
#define BB    4
#define CC    32
#define HH    32
#define WW    1024
#define PATCH 21
#define DIL   2
#define RAD   10            // (PATCH-1)/2
#define PADW  20            // DIL*RAD : max displacement
#define CHUNK 4             // channels staged per LDS pass
#define LROW  (WW + 2*PADW) // 1064 floats per staged x2 row (16B-aligned stride: 1064%4==0)

// One block: (b, h, pi, tap-group). 256 threads, thread t covers w = 4t..4t+3.
// Tap group computes TPT consecutive pj starting at PJ0 (2*PJ0 multiple of 4 => aligned windows).
template <int PJ0, int TPT>
__device__ __forceinline__ void corr_body(const float* __restrict__ x1,
                                          const float* __restrict__ x2,
                                          float* __restrict__ out) {
    const int tid = threadIdx.x;
    const int h   = blockIdx.x;
    const int bp  = blockIdx.y;           // b*PATCH + pi
    const int b   = bp / PATCH;
    const int pi  = bp % PATCH;
    const int r2  = h + DIL * (pi - RAD); // x2 source row
    const int w4  = tid * 4;

    float* outp = out + (((size_t)(b * PATCH * PATCH + pi * PATCH + PJ0)) * HH + h) * WW + w4;

    if (r2 < 0 || r2 >= HH) {
        // whole displacement row out of range -> zeros (leaky_relu(0)=0)
        float4 z = make_float4(0.f, 0.f, 0.f, 0.f);
#pragma unroll
        for (int j = 0; j < TPT; j++)
            *(float4*)(outp + (size_t)j * HH * WW) = z;
        return;
    }

    __shared__ float sx2[CHUNK][LROW];

    const float* x1p = x1 + (((size_t)(b * CC) * HH + h) * WW) + w4;  // + c*HH*WW
    const float* x2p = x2 + (((size_t)(b * CC) * HH + r2) * WW);      // + c*HH*WW + u

    float acc[TPT][4];
#pragma unroll
    for (int j = 0; j < TPT; j++)
#pragma unroll
        for (int k = 0; k < 4; k++) acc[j][k] = 0.f;

    for (int cc = 0; cc < CC; cc += CHUNK) {
        __syncthreads();
        // Stage CHUNK x2 rows with +/-20 halo, zero-padded. All float4-granular:
        // u = 4*i - 20; boundaries (0, 1024) are multiples of 4 -> each float4 fully in or out.
        for (int idx = tid; idx < CHUNK * (LROW / 4); idx += 256) {
            int c  = idx / (LROW / 4);
            int i4 = idx - c * (LROW / 4);
            int u  = i4 * 4 - PADW;
            float4 v = make_float4(0.f, 0.f, 0.f, 0.f);
            if (u >= 0 && u <= WW - 4)
                v = *(const float4*)(x2p + (size_t)(cc + c) * HH * WW + u);
            *(float4*)&sx2[c][i4 * 4] = v;
        }
        __syncthreads();

#pragma unroll
        for (int c = 0; c < CHUNK; c++) {
            float4 av = *(const float4*)(x1p + (size_t)(cc + c) * HH * WW);
            const float a[4] = {av.x, av.y, av.z, av.w};

            constexpr int WFL = 4 + 2 * (TPT - 1);   // window floats needed
            constexpr int WV  = (WFL + 3) / 4;       // float4 (ds_read_b128) count
            float win[WV * 4];
            // LDS index of u = w + 2*(pj-RAD) is u + PADW = w4 + 2*pj ; start = w4 + 2*PJ0 (16B aligned)
            const float* wbase = &sx2[c][w4 + 2 * PJ0];
#pragma unroll
            for (int v = 0; v < WV; v++)
                *(float4*)&win[v * 4] = *(const float4*)(wbase + v * 4);

#pragma unroll
            for (int j = 0; j < TPT; j++)
#pragma unroll
                for (int k = 0; k < 4; k++)
                    acc[j][k] = fmaf(a[k], win[2 * j + k], acc[j][k]);
        }
    }

    const float inv_c = 1.0f / (float)CC;
#pragma unroll
    for (int j = 0; j < TPT; j++) {
        float4 o;
        float* ov = (float*)&o;
#pragma unroll
        for (int k = 0; k < 4; k++) {
            float v = acc[j][k] * inv_c;
            ov[k] = v > 0.f ? v : 0.1f * v;
        }
        *(float4*)(outp + (size_t)j * HH * WW) = o;
    }
}

__global__ __launch_bounds__(256)
void corr_kernel(const float* __restrict__ x1, const float* __restrict__ x2,
                 float* __restrict__ out) {
    // blockIdx.z selects the tap group (block-uniform -> barriers are safe)
    if (blockIdx.z == 0)      corr_body<0, 8>(x1, x2, out);
    else if (blockIdx.z == 1) corr_body<8, 8>(x1, x2, out);
    else                      corr_body<16, 5>(x1, x2, out);
}

extern "C" void kernel_launch(void* const* d_in, const int* in_sizes, int n_in,
                              void* d_out, int out_size, void* d_ws, size_t ws_size,
                              hipStream_t stream) {
    const float* x1 = (const float*)d_in[0];
    const float* x2 = (const float*)d_in[1];
    float* out = (float*)d_out;

    dim3 grid(HH, BB * PATCH, 3);
    dim3 block(256, 1, 1);
    corr_kernel<<<grid, block, 0, stream>>>(x1, x2, out);
}

// Round 2
// 327.470 us; speedup vs baseline: 1.1860x; 1.1860x over previous
//
#include <hip/hip_runtime.h>

// Problem constants (match reference)
#define BB    4
#define CC    32
#define HH    32
#define WW    1024
#define PATCH 21
#define DIL   2
#define RAD   10            // (PATCH-1)/2
#define PADW  20            // DIL*RAD : max displacement
#define CHUNK 4             // channels staged per LDS pass
#define LROW  (WW + 2*PADW) // 1064 floats per staged x2 row (16B-aligned stride: 1064%4==0)

// One block: (b, h, pi, tap-group). 256 threads, thread t covers w = 4t..4t+3.
// Tap group computes TPT consecutive pj starting at PJ0 (2*PJ0 multiple of 4 => aligned windows).
// NOTE: the LDS buffer is declared ONCE in the kernel and passed in — three
// separate __shared__ statics per template instantiation cost 51 KB/block and
// capped occupancy at 3 blocks/CU (R1 lesson).
template <int PJ0, int TPT>
__device__ __forceinline__ void corr_body(const float* __restrict__ x1,
                                          const float* __restrict__ x2,
                                          float* __restrict__ out,
                                          float* __restrict__ sx2 /* [CHUNK*LROW] LDS */) {
    const int tid = threadIdx.x;
    const int h   = blockIdx.x;
    const int bp  = blockIdx.y;           // b*PATCH + pi
    const int b   = bp / PATCH;
    const int pi  = bp - b * PATCH;
    const int r2  = h + DIL * (pi - RAD); // x2 source row
    const int w4  = tid * 4;

    float* outp = out + (((size_t)(b * PATCH * PATCH + pi * PATCH + PJ0)) * HH + h) * WW + w4;

    if (r2 < 0 || r2 >= HH) {
        // whole displacement row out of range -> zeros (leaky_relu(0)=0)
        float4 z = make_float4(0.f, 0.f, 0.f, 0.f);
#pragma unroll
        for (int j = 0; j < TPT; j++)
            *(float4*)(outp + (size_t)j * HH * WW) = z;
        return;
    }

    const float* x1p = x1 + (((size_t)(b * CC) * HH + h) * WW) + w4;  // + c*HH*WW
    const float* x2p = x2 + (((size_t)(b * CC) * HH + r2) * WW);      // + c*HH*WW + u

    float acc[TPT][4];
#pragma unroll
    for (int j = 0; j < TPT; j++)
#pragma unroll
        for (int k = 0; k < 4; k++) acc[j][k] = 0.f;

    for (int cc = 0; cc < CC; cc += CHUNK) {
        __syncthreads();
        // Stage CHUNK x2 rows with +/-20 halo, zero-padded. All float4-granular:
        // u = 4*i - 20; boundaries (0, 1024) are multiples of 4 -> each float4 fully in or out.
        for (int idx = tid; idx < CHUNK * (LROW / 4); idx += 256) {
            int c  = idx / (LROW / 4);
            int i4 = idx - c * (LROW / 4);
            int u  = i4 * 4 - PADW;
            float4 v = make_float4(0.f, 0.f, 0.f, 0.f);
            if (u >= 0 && u <= WW - 4)
                v = *(const float4*)(x2p + (size_t)(cc + c) * HH * WW + u);
            *(float4*)&sx2[c * LROW + i4 * 4] = v;
        }
        __syncthreads();

#pragma unroll
        for (int c = 0; c < CHUNK; c++) {
            float4 av = *(const float4*)(x1p + (size_t)(cc + c) * HH * WW);
            const float a[4] = {av.x, av.y, av.z, av.w};

            constexpr int WFL = 4 + 2 * (TPT - 1);   // window floats needed
            constexpr int WV  = (WFL + 3) / 4;       // float4 (ds_read_b128) count
            float win[WV * 4];
            // LDS index of u = w + 2*(pj-RAD) is u + PADW = w4 + 2*pj ; start = w4 + 2*PJ0 (16B aligned)
            const float* wbase = &sx2[c * LROW + w4 + 2 * PJ0];
#pragma unroll
            for (int v = 0; v < WV; v++)
                *(float4*)&win[v * 4] = *(const float4*)(wbase + v * 4);

#pragma unroll
            for (int j = 0; j < TPT; j++)
#pragma unroll
                for (int k = 0; k < 4; k++)
                    acc[j][k] = fmaf(a[k], win[2 * j + k], acc[j][k]);
        }
    }

    const float inv_c = 1.0f / (float)CC;
#pragma unroll
    for (int j = 0; j < TPT; j++) {
        float4 o;
        float* ov = (float*)&o;
#pragma unroll
        for (int k = 0; k < 4; k++) {
            float v = acc[j][k] * inv_c;
            ov[k] = v > 0.f ? v : 0.1f * v;
        }
        *(float4*)(outp + (size_t)j * HH * WW) = o;
    }
}

// __launch_bounds__(256, 8): 8 waves/EU => 8 blocks/CU target; caps VGPR at 64
// (was 68 without it). LDS 17 KB/block allows 9 blocks, so VGPR is the binding
// constraint for full 32-wave residency.
__global__ __launch_bounds__(256, 8)
void corr_kernel(const float* __restrict__ x1, const float* __restrict__ x2,
                 float* __restrict__ out) {
    __shared__ float sx2[CHUNK * LROW];   // single 17 KB buffer shared by all tap groups
    // blockIdx.z selects the tap group (block-uniform -> barriers are safe)
    if (blockIdx.z == 0)      corr_body<0, 8>(x1, x2, out, sx2);
    else if (blockIdx.z == 1) corr_body<8, 8>(x1, x2, out, sx2);
    else                      corr_body<16, 5>(x1, x2, out, sx2);
}

extern "C" void kernel_launch(void* const* d_in, const int* in_sizes, int n_in,
                              void* d_out, int out_size, void* d_ws, size_t ws_size,
                              hipStream_t stream) {
    const float* x1 = (const float*)d_in[0];
    const float* x2 = (const float*)d_in[1];
    float* out = (float*)d_out;

    dim3 grid(HH, BB * PATCH, 3);
    dim3 block(256, 1, 1);
    corr_kernel<<<grid, block, 0, stream>>>(x1, x2, out);
}